// Round 7
// baseline (29.459 us; speedup 1.0000x reference)
//
#include <hip/hip_runtime.h>
#include <hip/hip_bf16.h>
#include <stdint.h>

#define Bn 256
#define Sn 512
#define Hn 768
#define Pn 32
#define Kn 3072   // 4*H

typedef __attribute__((ext_vector_type(8))) short short8;
typedef __attribute__((ext_vector_type(4))) float f32x4;

__device__ __forceinline__ unsigned short f2bf(float f) {
    union { float f; unsigned int u; } v;
    v.f = f;
    unsigned int r = v.u + 0x7FFFu + ((v.u >> 16) & 1u);  // RNE
    return (unsigned short)(r >> 16);
}

__device__ __forceinline__ void gload_lds16(const void* src, void* lds) {
    __builtin_amdgcn_global_load_lds(
        (const __attribute__((address_space(1))) unsigned int*)src,
        (__attribute__((address_space(3))) unsigned int*)lds, 16, 0, 0);
}

// K1: masked-mean pool + cls + concat + L2-normalize -> bf16 normb[256][3072].
// (R6-proven: ballot-compacted, row-0-padded unconditional 8-deep gather.)
__global__ __launch_bounds__(384) void k_pool_norm(
    const float* __restrict__ pv, const float* __restrict__ mv,
    const int* __restrict__ apos, unsigned short* __restrict__ normb)
{
    const int b   = blockIdx.x;
    const int tid = threadIdx.x;

    __shared__ int   cpos[Pn + 8];
    __shared__ int   scnt, spad;
    __shared__ float swsum[6];
    __shared__ float sinv;

    if (tid < 64) {
        int q = (tid < Pn) ? apos[b * Pn + tid] : -1;
        const unsigned long long m = __ballot(q >= 0);
        const int c = __popcll(m);
        if (q >= 0) {
            const int rank = __popcll(m & ((1ull << tid) - 1ull));
            cpos[rank] = q;
        }
        const int pad = (8 - (c & 7)) & 7;
        if (tid < pad) cpos[c + tid] = 0;
        if (tid == 0) { scnt = c; spad = c + pad; }
    }
    __syncthreads();
    const int cnt = scnt, padded = spad;
    const float invc = 1.0f / (float)(cnt < 1 ? 1 : cnt);

    const float* src  = (tid < 192) ? pv : mv;
    const int    col4 = (tid < 192) ? tid : (tid - 192);
    const size_t base = (size_t)b * ((size_t)Sn * Hn) + (size_t)col4 * 4;

    float4 acc = make_float4(0.f, 0.f, 0.f, 0.f);
    for (int p0 = 0; p0 < padded; p0 += 8) {
        float4 g[8];
        #pragma unroll
        for (int j = 0; j < 8; ++j)
            g[j] = *(const float4*)(src + base + (size_t)cpos[p0 + j] * Hn);
        #pragma unroll
        for (int j = 0; j < 8; ++j) {
            acc.x += g[j].x; acc.y += g[j].y; acc.z += g[j].z; acc.w += g[j].w;
        }
    }
    float4 cls = *(const float4*)(src + base);
    const float e = (float)(padded - cnt);
    acc.x -= e * cls.x; acc.y -= e * cls.y; acc.z -= e * cls.z; acc.w -= e * cls.w;
    float4 pool = make_float4(acc.x * invc, acc.y * invc, acc.z * invc, acc.w * invc);

    float sq = pool.x*pool.x + pool.y*pool.y + pool.z*pool.z + pool.w*pool.w
             + cls.x*cls.x  + cls.y*cls.y  + cls.z*cls.z  + cls.w*cls.w;
    #pragma unroll
    for (int off = 32; off > 0; off >>= 1) sq += __shfl_down(sq, off);
    if ((tid & 63) == 0) swsum[tid >> 6] = sq;
    __syncthreads();
    if (tid == 0) {
        float t = swsum[0] + swsum[1] + swsum[2] + swsum[3] + swsum[4] + swsum[5];
        sinv = 1.0f / fmaxf(sqrtf(t), 1e-12f);
    }
    __syncthreads();
    const float s = sinv;

    const int sect = (tid < 192) ? 0 : 2;
    unsigned short* o = normb + (size_t)b * Kn;
    ushort4 u0, u1;
    u0.x = f2bf(pool.x * s); u0.y = f2bf(pool.y * s); u0.z = f2bf(pool.z * s); u0.w = f2bf(pool.w * s);
    u1.x = f2bf(cls.x  * s); u1.y = f2bf(cls.y  * s); u1.z = f2bf(cls.z  * s); u1.w = f2bf(cls.w  * s);
    *(ushort4*)(o + sect * Hn + col4 * 4)       = u0;
    *(ushort4*)(o + (sect + 1) * Hn + col4 * 4) = u1;
}

// K2: partial[ks][256][768] = normb @ w1^T, BM=256 (W read ONCE), BN=64, KSPLIT=8.
// Grid 96 blocks. 4 waves; wave owns 64 rows x 64 cols (4x4 fragments, 32 MFMA/step).
// A: global_load_lds bf16, linear dest + inverse-swizzled source (G21).
// B: reg-staged from f32 W, cvt + swizzled ds_write_b128, T14 issue-early/write-late.
#define KSPLIT 8
#define NS 6   // 384 / 64
__global__ __launch_bounds__(256) void k_gemm(
    const unsigned short* __restrict__ A,   // normb [256][3072]
    const float* __restrict__ W,            // fc1_w [768][3072] f32
    float* __restrict__ part,               // [8][256][768]
    const float* __restrict__ b2, float* __restrict__ out)
{
    __shared__ __align__(16) unsigned short Al[2][256 * 64];  // 2 x 32 KB
    __shared__ __align__(16) unsigned short Bl[2][64 * 64];   // 2 x 8 KB

    const int bid = blockIdx.x;
    const int ks = bid & 7;
    const int nt = bid >> 3;                 // 0..11
    const int n0 = nt * 64, k0 = ks * 384;

    const int tid  = threadIdx.x;
    const int w    = tid >> 6, lane = tid & 63;
    const int r    = lane & 15, g = lane >> 4;

    if (bid == 0) out[tid] = b2[0];   // init for K_C atomic accumulation

    // B staging geometry (2 chunks/thread): id2 = c*256+tid
    int brow[2], bkgl[2];
    #pragma unroll
    for (int c = 0; c < 2; ++c) {
        const int id2 = c * 256 + tid;
        brow[c] = id2 >> 3;
        bkgl[c] = id2 & 7;
    }

    f32x4 acc[4][4];
    #pragma unroll
    for (int i = 0; i < 4; ++i)
        #pragma unroll
        for (int j = 0; j < 4; ++j) acc[i][j] = (f32x4){0.f, 0.f, 0.f, 0.f};

    // ---- prologue: stage step 0 into buf 0 ----
    #pragma unroll
    for (int c = 0; c < 8; ++c) {
        const int id = c * 256 + tid;
        const int row = id >> 3;
        const int kg = (id & 7) ^ (row & 7);
        gload_lds16(A + (size_t)row * Kn + k0 + kg * 8, &Al[0][c * 2048 + w * 512]);
    }
    #pragma unroll
    for (int c = 0; c < 2; ++c) {
        const float* wp = W + (size_t)(n0 + brow[c]) * Kn + k0 + bkgl[c] * 8;
        const float4 fa = *(const float4*)wp;
        const float4 fb = *(const float4*)(wp + 4);
        short8 cc;
        cc[0]=(short)f2bf(fa.x); cc[1]=(short)f2bf(fa.y); cc[2]=(short)f2bf(fa.z); cc[3]=(short)f2bf(fa.w);
        cc[4]=(short)f2bf(fb.x); cc[5]=(short)f2bf(fb.y); cc[6]=(short)f2bf(fb.z); cc[7]=(short)f2bf(fb.w);
        *(short8*)&Bl[0][brow[c] * 64 + (bkgl[c] ^ (brow[c] & 7)) * 8] = cc;
    }

    int cur = 0;
    for (int s = 0; s < NS; ++s) {
        __syncthreads();   // buf[cur] ready (barrier drains vmcnt + lgkm)
        float4 nf[2][2];
        if (s + 1 < NS) {
            const int ko = (s + 1) * 64;
            #pragma unroll
            for (int c = 0; c < 8; ++c) {
                const int id = c * 256 + tid;
                const int row = id >> 3;
                const int kg = (id & 7) ^ (row & 7);
                gload_lds16(A + (size_t)row * Kn + k0 + ko + kg * 8,
                            &Al[cur ^ 1][c * 2048 + w * 512]);
            }
            #pragma unroll
            for (int c = 0; c < 2; ++c) {
                const float* wp = W + (size_t)(n0 + brow[c]) * Kn + k0 + ko + bkgl[c] * 8;
                nf[c][0] = *(const float4*)wp;
                nf[c][1] = *(const float4*)(wp + 4);
            }
        }
        #pragma unroll
        for (int kq = 0; kq < 2; ++kq) {
            short8 af[4], bf[4];
            #pragma unroll
            for (int ma = 0; ma < 4; ++ma) {
                const int row = w * 64 + ma * 16 + r;
                const int slot = (kq * 4 + g) ^ (row & 7);
                af[ma] = *(const short8*)&Al[cur][row * 64 + slot * 8];
            }
            #pragma unroll
            for (int nb = 0; nb < 4; ++nb) {
                const int row = nb * 16 + r;
                const int slot = (kq * 4 + g) ^ (row & 7);
                bf[nb] = *(const short8*)&Bl[cur][row * 64 + slot * 8];
            }
            #pragma unroll
            for (int ma = 0; ma < 4; ++ma)
                #pragma unroll
                for (int nb = 0; nb < 4; ++nb)
                    acc[ma][nb] = __builtin_amdgcn_mfma_f32_16x16x32_bf16(
                        af[ma], bf[nb], acc[ma][nb], 0, 0, 0);
        }
        if (s + 1 < NS) {   // convert + write AFTER compute (loads arrived)
            #pragma unroll
            for (int c = 0; c < 2; ++c) {
                short8 cc;
                cc[0]=(short)f2bf(nf[c][0].x); cc[1]=(short)f2bf(nf[c][0].y);
                cc[2]=(short)f2bf(nf[c][0].z); cc[3]=(short)f2bf(nf[c][0].w);
                cc[4]=(short)f2bf(nf[c][1].x); cc[5]=(short)f2bf(nf[c][1].y);
                cc[6]=(short)f2bf(nf[c][1].z); cc[7]=(short)f2bf(nf[c][1].w);
                *(short8*)&Bl[cur ^ 1][brow[c] * 64 + (bkgl[c] ^ (brow[c] & 7)) * 8] = cc;
            }
        }
        cur ^= 1;
    }

    float* o = part + (size_t)ks * (Bn * Hn);
    #pragma unroll
    for (int ma = 0; ma < 4; ++ma) {
        #pragma unroll
        for (int nb = 0; nb < 4; ++nb) {
            const int orow = w * 64 + ma * 16 + g * 4;
            const int ocol = n0 + nb * 16 + r;
            #pragma unroll
            for (int i = 0; i < 4; ++i)
                o[(size_t)(orow + i) * Hn + ocol] = acc[ma][nb][i];
        }
    }
}

// K_C: fused fold(8 partials) + BN stats + BN-apply + ReLU + fc2 (R6-proven).
__global__ __launch_bounds__(256) void k_bnfc2(
    const float* __restrict__ part, const float* __restrict__ gamma,
    const float* __restrict__ beta, const float* __restrict__ w2,
    float* __restrict__ out)
{
    const int blk = blockIdx.x;
    const int fo = threadIdx.x & 15, rg = threadIdx.x >> 4;
    const int f = blk * 16 + fo;
    const float* p = part + f;

    float y[16];
    float s = 0.f, s2 = 0.f;
    #pragma unroll
    for (int i = 0; i < 16; ++i) {
        const size_t off = (size_t)(rg * 16 + i) * Hn;
        float v = 0.f;
        #pragma unroll
        for (int j = 0; j < KSPLIT; ++j) v += p[(size_t)j * (Bn * Hn) + off];
        y[i] = v;
        s += v; s2 += v * v;
    }

    __shared__ float S[16][16], S2[16][16];
    __shared__ float sc_s[16], sh_s[16], w2_s[16];
    S[rg][fo] = s; S2[rg][fo] = s2;
    __syncthreads();
    if (threadIdx.x < 16) {
        const int ff = blk * 16 + threadIdx.x;
        float ts = 0.f, ts2 = 0.f;
        #pragma unroll
        for (int i = 0; i < 16; ++i) { ts += S[i][threadIdx.x]; ts2 += S2[i][threadIdx.x]; }
        const float mean = ts * (1.0f / 256.0f);
        const float var  = fmaxf(ts2 * (1.0f / 256.0f) - mean * mean, 0.0f);
        const float sc   = gamma[ff] / sqrtf(var + 1e-5f);
        sc_s[threadIdx.x] = sc;
        sh_s[threadIdx.x] = beta[ff] - mean * sc;
        w2_s[threadIdx.x] = w2[ff];
    }
    __syncthreads();

    const float sc = sc_s[fo], sh = sh_s[fo], wv = w2_s[fo];
    __shared__ float R[256][17];
    #pragma unroll
    for (int i = 0; i < 16; ++i)
        R[rg * 16 + i][fo] = fmaxf(y[i] * sc + sh, 0.f) * wv;
    __syncthreads();

    float rs = 0.f;
    #pragma unroll
    for (int j = 0; j < 16; ++j) rs += R[threadIdx.x][j];
    atomicAdd(out + threadIdx.x, rs);
}

extern "C" void kernel_launch(void* const* d_in, const int* in_sizes, int n_in,
                              void* d_out, int out_size, void* d_ws, size_t ws_size,
                              hipStream_t stream)
{
    const float* pv    = (const float*)d_in[0];
    const float* mv    = (const float*)d_in[1];
    const int*   apos  = (const int*)d_in[2];
    const float* w1    = (const float*)d_in[3];
    const float* w2    = (const float*)d_in[5];
    const float* b2    = (const float*)d_in[6];
    const float* gamma = (const float*)d_in[7];
    const float* beta  = (const float*)d_in[8];

    char* ws = (char*)d_ws;
    unsigned short* normb = (unsigned short*)ws;               // 1,572,864 B
    float*          part  = (float*)(ws + 1572864);            // 6,291,456 B

    hipLaunchKernelGGL(k_pool_norm, dim3(Bn), dim3(384), 0, stream, pv, mv, apos, normb);
    hipLaunchKernelGGL(k_gemm,      dim3(96), dim3(256), 0, stream, normb, w1, part, b2, (float*)d_out);
    hipLaunchKernelGGL(k_bnfc2,     dim3(48), dim3(256), 0, stream, part, gamma, beta, w2, (float*)d_out);
}

// Round 8
// 25.270 us; speedup vs baseline: 1.1658x; 1.1658x over previous
//
#include <hip/hip_runtime.h>
#include <hip/hip_bf16.h>
#include <stdint.h>

#define Bn 256
#define Sn 512
#define Hn 768
#define Pn 32
#define Kn 3072   // 4*H

typedef __attribute__((ext_vector_type(8))) short short8;
typedef __attribute__((ext_vector_type(4))) float f32x4;

__device__ __forceinline__ unsigned short f2bf(float f) {
    union { float f; unsigned int u; } v;
    v.f = f;
    unsigned int r = v.u + 0x7FFFu + ((v.u >> 16) & 1u);  // RNE
    return (unsigned short)(r >> 16);
}

__device__ __forceinline__ void gload_lds16(const void* src, void* lds) {
    __builtin_amdgcn_global_load_lds(
        (const __attribute__((address_space(1))) unsigned int*)src,
        (__attribute__((address_space(3))) unsigned int*)lds, 16, 0, 0);
}

// K1: masked-mean pool + cls + concat + L2-normalize -> bf16 normb[256][3072].
// (R6-proven: ballot-compacted, row-0-padded unconditional 8-deep gather.)
__global__ __launch_bounds__(384) void k_pool_norm(
    const float* __restrict__ pv, const float* __restrict__ mv,
    const int* __restrict__ apos, unsigned short* __restrict__ normb)
{
    const int b   = blockIdx.x;
    const int tid = threadIdx.x;

    __shared__ int   cpos[Pn + 8];
    __shared__ int   scnt, spad;
    __shared__ float swsum[6];
    __shared__ float sinv;

    if (tid < 64) {
        int q = (tid < Pn) ? apos[b * Pn + tid] : -1;
        const unsigned long long m = __ballot(q >= 0);
        const int c = __popcll(m);
        if (q >= 0) {
            const int rank = __popcll(m & ((1ull << tid) - 1ull));
            cpos[rank] = q;
        }
        const int pad = (8 - (c & 7)) & 7;
        if (tid < pad) cpos[c + tid] = 0;
        if (tid == 0) { scnt = c; spad = c + pad; }
    }
    __syncthreads();
    const int cnt = scnt, padded = spad;
    const float invc = 1.0f / (float)(cnt < 1 ? 1 : cnt);

    const float* src  = (tid < 192) ? pv : mv;
    const int    col4 = (tid < 192) ? tid : (tid - 192);
    const size_t base = (size_t)b * ((size_t)Sn * Hn) + (size_t)col4 * 4;

    float4 acc = make_float4(0.f, 0.f, 0.f, 0.f);
    for (int p0 = 0; p0 < padded; p0 += 8) {
        float4 g[8];
        #pragma unroll
        for (int j = 0; j < 8; ++j)
            g[j] = *(const float4*)(src + base + (size_t)cpos[p0 + j] * Hn);
        #pragma unroll
        for (int j = 0; j < 8; ++j) {
            acc.x += g[j].x; acc.y += g[j].y; acc.z += g[j].z; acc.w += g[j].w;
        }
    }
    float4 cls = *(const float4*)(src + base);
    const float e = (float)(padded - cnt);
    acc.x -= e * cls.x; acc.y -= e * cls.y; acc.z -= e * cls.z; acc.w -= e * cls.w;
    float4 pool = make_float4(acc.x * invc, acc.y * invc, acc.z * invc, acc.w * invc);

    float sq = pool.x*pool.x + pool.y*pool.y + pool.z*pool.z + pool.w*pool.w
             + cls.x*cls.x  + cls.y*cls.y  + cls.z*cls.z  + cls.w*cls.w;
    #pragma unroll
    for (int off = 32; off > 0; off >>= 1) sq += __shfl_down(sq, off);
    if ((tid & 63) == 0) swsum[tid >> 6] = sq;
    __syncthreads();
    if (tid == 0) {
        float t = swsum[0] + swsum[1] + swsum[2] + swsum[3] + swsum[4] + swsum[5];
        sinv = 1.0f / fmaxf(sqrtf(t), 1e-12f);
    }
    __syncthreads();
    const float s = sinv;

    const int sect = (tid < 192) ? 0 : 2;
    unsigned short* o = normb + (size_t)b * Kn;
    ushort4 u0, u1;
    u0.x = f2bf(pool.x * s); u0.y = f2bf(pool.y * s); u0.z = f2bf(pool.z * s); u0.w = f2bf(pool.w * s);
    u1.x = f2bf(cls.x  * s); u1.y = f2bf(cls.y  * s); u1.z = f2bf(cls.z  * s); u1.w = f2bf(cls.w  * s);
    *(ushort4*)(o + sect * Hn + col4 * 4)       = u0;
    *(ushort4*)(o + (sect + 1) * Hn + col4 * 4) = u1;
}

// K2: partial[ks][256][768] = normb @ w1^T, KSPLIT=8, BM=64, BN=64, BK=128, NS=3.
// Grid 384 (full CU coverage), 4 waves (2x2), wave = 32x32 via 2x2 frags x 4 kq.
// A: global_load_lds bf16, linear LDS dest + inverse-swizzled global src (G21).
// B: reg-staged from f32 W (T14 issue-early/write-late), swizzled ds_write_b128.
// Swizzle: 16 slots/row, slot = chunk ^ (row&7) (low-3-bit XOR, involution).
#define KSPLIT 8
#define NS 3   // 384 / 128
__global__ __launch_bounds__(256) void k_gemm(
    const unsigned short* __restrict__ A,   // normb [256][3072]
    const float* __restrict__ W,            // fc1_w [768][3072] f32
    float* __restrict__ part,               // [8][256][768]
    const float* __restrict__ b2, float* __restrict__ out)
{
    __shared__ __align__(16) unsigned short Al[2][64 * 128];  // 2 x 16 KB
    __shared__ __align__(16) unsigned short Bl[2][64 * 128];  // 2 x 16 KB

    const int bid = blockIdx.x;
    const int ks = bid & 7;
    const int mt = (bid >> 3) & 3;
    const int nt = bid >> 5;                 // 0..11
    const int m0 = mt * 64, n0 = nt * 64, k0 = ks * 384;

    const int tid  = threadIdx.x;
    const int w    = tid >> 6, lane = tid & 63;
    const int r    = lane & 15, g = lane >> 4;
    const int wm   = w >> 1,  wn = w & 1;

    if (bid == 0) out[tid] = b2[0];   // init for K_C atomic accumulation

    // staging geometry: 4 chunks/thread each for A and B (64 rows x 16 slots)
    int arow[4], asl[4], brow[4], bsl[4];
    #pragma unroll
    for (int c = 0; c < 4; ++c) {
        const int id = c * 256 + tid;
        arow[c] = id >> 4;
        asl[c]  = (id & 15) ^ (arow[c] & 7);   // inverse-swizzled global chunk for linear dest
        brow[c] = id >> 4;
        bsl[c]  = (id & 15) ^ (brow[c] & 7);   // swizzled LDS slot for global chunk (id&15)
    }

    f32x4 acc[2][2] = {{{0.f,0.f,0.f,0.f},{0.f,0.f,0.f,0.f}},
                       {{0.f,0.f,0.f,0.f},{0.f,0.f,0.f,0.f}}};

    // ---- prologue: stage step 0 into buf 0 ----
    #pragma unroll
    for (int c = 0; c < 4; ++c)
        gload_lds16(A + (size_t)(m0 + arow[c]) * Kn + k0 + asl[c] * 8,
                    &Al[0][c * 2048 + w * 512]);
    #pragma unroll
    for (int c = 0; c < 4; ++c) {
        const float* wp = W + (size_t)(n0 + brow[c]) * Kn + k0 + (c * 256 + tid & 15) * 8;
        const float4 fa = *(const float4*)wp;
        const float4 fb = *(const float4*)(wp + 4);
        short8 cc;
        cc[0]=(short)f2bf(fa.x); cc[1]=(short)f2bf(fa.y); cc[2]=(short)f2bf(fa.z); cc[3]=(short)f2bf(fa.w);
        cc[4]=(short)f2bf(fb.x); cc[5]=(short)f2bf(fb.y); cc[6]=(short)f2bf(fb.z); cc[7]=(short)f2bf(fb.w);
        *(short8*)&Bl[0][brow[c] * 128 + bsl[c] * 8] = cc;
    }

    int cur = 0;
    for (int s = 0; s < NS; ++s) {
        __syncthreads();   // buf[cur] ready (barrier drains vmcnt + lgkm)
        float4 nf[4][2];
        if (s + 1 < NS) {
            const int ko = (s + 1) * 128;
            #pragma unroll
            for (int c = 0; c < 4; ++c)
                gload_lds16(A + (size_t)(m0 + arow[c]) * Kn + k0 + ko + asl[c] * 8,
                            &Al[cur ^ 1][c * 2048 + w * 512]);
            #pragma unroll
            for (int c = 0; c < 4; ++c) {
                const float* wp = W + (size_t)(n0 + brow[c]) * Kn + k0 + ko + ((c * 256 + tid) & 15) * 8;
                nf[c][0] = *(const float4*)wp;
                nf[c][1] = *(const float4*)(wp + 4);
            }
        }
        #pragma unroll
        for (int kq = 0; kq < 4; ++kq) {
            short8 af[2], bf[2];
            #pragma unroll
            for (int ma = 0; ma < 2; ++ma) {
                const int row = wm * 32 + ma * 16 + r;
                const int slot = (kq * 4 + g) ^ (row & 7);
                af[ma] = *(const short8*)&Al[cur][row * 128 + slot * 8];
            }
            #pragma unroll
            for (int nb = 0; nb < 2; ++nb) {
                const int row = wn * 32 + nb * 16 + r;
                const int slot = (kq * 4 + g) ^ (row & 7);
                bf[nb] = *(const short8*)&Bl[cur][row * 128 + slot * 8];
            }
            #pragma unroll
            for (int ma = 0; ma < 2; ++ma)
                #pragma unroll
                for (int nb = 0; nb < 2; ++nb)
                    acc[ma][nb] = __builtin_amdgcn_mfma_f32_16x16x32_bf16(
                        af[ma], bf[nb], acc[ma][nb], 0, 0, 0);
        }
        if (s + 1 < NS) {   // convert + write AFTER compute (loads arrived)
            #pragma unroll
            for (int c = 0; c < 4; ++c) {
                short8 cc;
                cc[0]=(short)f2bf(nf[c][0].x); cc[1]=(short)f2bf(nf[c][0].y);
                cc[2]=(short)f2bf(nf[c][0].z); cc[3]=(short)f2bf(nf[c][0].w);
                cc[4]=(short)f2bf(nf[c][1].x); cc[5]=(short)f2bf(nf[c][1].y);
                cc[6]=(short)f2bf(nf[c][1].z); cc[7]=(short)f2bf(nf[c][1].w);
                *(short8*)&Bl[cur ^ 1][brow[c] * 128 + bsl[c] * 8] = cc;
            }
        }
        cur ^= 1;
    }

    float* o = part + (size_t)ks * (Bn * Hn);
    #pragma unroll
    for (int ma = 0; ma < 2; ++ma) {
        #pragma unroll
        for (int nb = 0; nb < 2; ++nb) {
            const int orow = m0 + wm * 32 + ma * 16 + g * 4;
            const int ocol = n0 + wn * 32 + nb * 16 + r;
            #pragma unroll
            for (int i = 0; i < 4; ++i)
                o[(size_t)(orow + i) * Hn + ocol] = acc[ma][nb][i];
        }
    }
}

// K_C: fused fold(8 partials) + BN stats + BN-apply + ReLU + fc2 (R6-proven).
__global__ __launch_bounds__(256) void k_bnfc2(
    const float* __restrict__ part, const float* __restrict__ gamma,
    const float* __restrict__ beta, const float* __restrict__ w2,
    float* __restrict__ out)
{
    const int blk = blockIdx.x;
    const int fo = threadIdx.x & 15, rg = threadIdx.x >> 4;
    const int f = blk * 16 + fo;
    const float* p = part + f;

    float y[16];
    float s = 0.f, s2 = 0.f;
    #pragma unroll
    for (int i = 0; i < 16; ++i) {
        const size_t off = (size_t)(rg * 16 + i) * Hn;
        float v = 0.f;
        #pragma unroll
        for (int j = 0; j < KSPLIT; ++j) v += p[(size_t)j * (Bn * Hn) + off];
        y[i] = v;
        s += v; s2 += v * v;
    }

    __shared__ float S[16][16], S2[16][16];
    __shared__ float sc_s[16], sh_s[16], w2_s[16];
    S[rg][fo] = s; S2[rg][fo] = s2;
    __syncthreads();
    if (threadIdx.x < 16) {
        const int ff = blk * 16 + threadIdx.x;
        float ts = 0.f, ts2 = 0.f;
        #pragma unroll
        for (int i = 0; i < 16; ++i) { ts += S[i][threadIdx.x]; ts2 += S2[i][threadIdx.x]; }
        const float mean = ts * (1.0f / 256.0f);
        const float var  = fmaxf(ts2 * (1.0f / 256.0f) - mean * mean, 0.0f);
        const float sc   = gamma[ff] / sqrtf(var + 1e-5f);
        sc_s[threadIdx.x] = sc;
        sh_s[threadIdx.x] = beta[ff] - mean * sc;
        w2_s[threadIdx.x] = w2[ff];
    }
    __syncthreads();

    const float sc = sc_s[fo], sh = sh_s[fo], wv = w2_s[fo];
    __shared__ float R[256][17];
    #pragma unroll
    for (int i = 0; i < 16; ++i)
        R[rg * 16 + i][fo] = fmaxf(y[i] * sc + sh, 0.f) * wv;
    __syncthreads();

    float rs = 0.f;
    #pragma unroll
    for (int j = 0; j < 16; ++j) rs += R[threadIdx.x][j];
    atomicAdd(out + threadIdx.x, rs);
}

extern "C" void kernel_launch(void* const* d_in, const int* in_sizes, int n_in,
                              void* d_out, int out_size, void* d_ws, size_t ws_size,
                              hipStream_t stream)
{
    const float* pv    = (const float*)d_in[0];
    const float* mv    = (const float*)d_in[1];
    const int*   apos  = (const int*)d_in[2];
    const float* w1    = (const float*)d_in[3];
    const float* w2    = (const float*)d_in[5];
    const float* b2    = (const float*)d_in[6];
    const float* gamma = (const float*)d_in[7];
    const float* beta  = (const float*)d_in[8];

    char* ws = (char*)d_ws;
    unsigned short* normb = (unsigned short*)ws;               // 1,572,864 B
    float*          part  = (float*)(ws + 1572864);            // 6,291,456 B

    hipLaunchKernelGGL(k_pool_norm, dim3(Bn),  dim3(384), 0, stream, pv, mv, apos, normb);
    hipLaunchKernelGGL(k_gemm,      dim3(384), dim3(256), 0, stream, normb, w1, part, b2, (float*)d_out);
    hipLaunchKernelGGL(k_bnfc2,     dim3(48),  dim3(256), 0, stream, part, gamma, beta, w2, (float*)d_out);
}